// Round 4
// baseline (50.883 us; speedup 1.0000x reference)
//
#include <hip/hip_runtime.h>
#include <hip/hip_cooperative_groups.h>

namespace cg = cooperative_groups;

#define B_   4
#define K_   8
#define N_   4096       // H*W
#define DV_  32
#define NC_  256        // 2^K_

// ws: [0, 65536) int part_hist[64][256]; [65536, 81920) uchar codes (2-kernel fallback only)
#define WS_OFF_CODES 65536
#define WS_COOP      65536
#define WS_2K        81920

__device__ __forceinline__ int read_mask(const void* m, int layout, int idx) {
    if (layout == 0) return ((const int*)m)[idx] != 0;
    if (layout == 1) return ((const float*)m)[idx] != 0.0f;
    if (layout == 3) return ((const int*)m)[2 * idx] != 0;  // int64 LE low word
    return ((const unsigned char*)m)[idx] != 0;
}

// Every block scans the same leading 16 KB of the mask buffer (safe under all
// candidate layouts; the u8 buffer is exactly 16 KB) -> identical verdict.
__device__ __forceinline__ int detect_layout(const void* mask, int tid) {
    __shared__ int ok[3];  // 0:i32, 1:f32, 2:i64
    if (tid < 3) ok[tid] = 1;
    __syncthreads();
    const unsigned int* mi = (const unsigned int*)mask;
    int li32 = 1, lf32 = 1, li64 = 1;
    for (int i = tid; i < 4096; i += 256) {
        unsigned int v = mi[i];
        li32 &= (v <= 1u);
        lf32 &= (v == 0u || v == 0x3F800000u);
        li64 &= ((i & 1) ? (v == 0u) : (v <= 1u));
    }
    if (!li32) atomicAnd(&ok[0], 0);
    if (!lf32) atomicAnd(&ok[1], 0);
    if (!li64) atomicAnd(&ok[2], 0);
    __syncthreads();
    return ok[2] ? 3 : (ok[0] ? 0 : (ok[1] ? 1 : 2));
}

// Shared phase-2 body: reduce 16 partial hists -> butterfly -> write own slice.
__device__ __forceinline__ void ctx_and_write(
        const int* __restrict__ part, int mycode, int b, int slice,
        const float* __restrict__ V, const float* __restrict__ mv,
        const float* __restrict__ temperature, float* __restrict__ out,
        float* X /* NC_*33 LDS */, int* red /* 4 ints LDS */) {
    int tid = threadIdx.x;
    int c = 0;
#pragma unroll
    for (int j = 0; j < 16; ++j) c += part[(b * 16 + j) * NC_ + tid];
    float cf = (float)c;

    int s = c;
#pragma unroll
    for (int off = 32; off; off >>= 1) s += __shfl_down(s, off);
    if ((tid & 63) == 0) red[tid >> 6] = s;
    __syncthreads();
    int evid = red[0] + red[1] + red[2] + red[3];

    float temp = fmaxf(temperature[0], 0.1f);
    float t = __expf(-1.0f / temp);

    // X[c][0..31] = cnt[c]*V[c][d], X[c][32] = cnt[c]   (row stride 33)
#pragma unroll
    for (int r = 0; r < 33; ++r) {
        float v = (r < DV_) ? cf * V[tid * DV_ + r] : cf;
        X[tid * 33 + r] = v;
    }
    __syncthreads();

    // 8 butterfly stages of [[1,t],[t,1]]^{(x)8}
#pragma unroll
    for (int stg = 0; stg < 8; ++stg) {
        int bit = 1 << stg;
        for (int p = tid; p < 128 * 33; p += 256) {
            int pi = p / 33, col = p - pi * 33;
            int c0 = ((pi >> stg) << (stg + 1)) | (pi & (bit - 1));
            int i0 = c0 * 33 + col, i1 = i0 + bit * 33;
            float x0 = X[i0], x1 = X[i1];
            X[i0] = fmaf(t, x1, x0);
            X[i1] = fmaf(t, x0, x1);
        }
        __syncthreads();
    }

    float* ob = out + (size_t)b * DV_ * N_ + (slice << 8) + tid;
    if (evid == 0) {
#pragma unroll
        for (int d = 0; d < DV_; ++d) ob[d * N_] = mv[d];
    } else {
        float rden = 1.0f / X[mycode * 33 + DV_];
#pragma unroll
        for (int d = 0; d < DV_; ++d) ob[d * N_] = X[mycode * 33 + d] * rden;
    }
}

// Cooperative single-dispatch kernel. grid = B_*16 x 256. One (b,n) per thread.
__global__ void __launch_bounds__(256)
coop_one(const float* __restrict__ z, const void* mask, const float* __restrict__ V,
         const float* __restrict__ mv, const float* __restrict__ temperature,
         float* __restrict__ out, int* __restrict__ part) {
    __shared__ float X[NC_ * 33];
    __shared__ int hist[NC_];
    __shared__ int red[4];
    int tid = threadIdx.x;
    int b = blockIdx.x >> 4;
    int slice = blockIdx.x & 15;
    int n = (slice << 8) + tid;

    int layout = detect_layout(mask, tid);   // contains syncthreads
    hist[tid] = 0;
    __syncthreads();

    const float* zb = z + (size_t)b * K_ * N_ + n;
    int mycode = 0;
#pragma unroll
    for (int j = 0; j < K_; ++j) mycode |= (zb[j * N_] > 0.5f ? 1 : 0) << j;
    if (read_mask(mask, layout, b * N_ + n)) atomicAdd(&hist[mycode], 1);
    __syncthreads();
    part[blockIdx.x * NC_ + tid] = hist[tid];

    cg::this_grid().sync();

    ctx_and_write(part, mycode, b, slice, V, mv, temperature, out, X, red);
}

// ---- fallback path A: two kernels (proven R2 structure) ----
__global__ void k1_codes_hist(const float* __restrict__ z, const void* mask,
                              int* __restrict__ part, unsigned char* __restrict__ codes) {
    __shared__ int hist[NC_];
    int tid = threadIdx.x;
    int b = blockIdx.x >> 4;
    int n = ((blockIdx.x & 15) << 8) + tid;
    int layout = detect_layout(mask, tid);
    hist[tid] = 0;
    __syncthreads();
    const float* zb = z + (size_t)b * K_ * N_ + n;
    int code = 0;
#pragma unroll
    for (int j = 0; j < K_; ++j) code |= (zb[j * N_] > 0.5f ? 1 : 0) << j;
    codes[b * N_ + n] = (unsigned char)code;
    if (read_mask(mask, layout, b * N_ + n)) atomicAdd(&hist[code], 1);
    __syncthreads();
    part[blockIdx.x * NC_ + tid] = hist[tid];
}

__global__ void __launch_bounds__(256)
k2_ctx_gather(const int* __restrict__ part, const unsigned char* __restrict__ codes,
              const float* __restrict__ V, const float* __restrict__ mv,
              const float* __restrict__ temperature, float* __restrict__ out) {
    __shared__ float X[NC_ * 33];
    __shared__ int red[4];
    int tid = threadIdx.x;
    int b = blockIdx.x >> 4;
    int slice = blockIdx.x & 15;
    int mycode = codes[b * N_ + (slice << 8) + tid];
    ctx_and_write(part, mycode, b, slice, V, mv, temperature, out, X, red);
}

// ---- fallback path B: zero-workspace, one block per batch ----
__global__ void __launch_bounds__(1024)
fused_all(const float* __restrict__ z, const void* mask, const float* __restrict__ V,
          const float* __restrict__ mask_value, const float* __restrict__ temperature,
          float* __restrict__ out) {
    __shared__ unsigned short codesL[N_];
    __shared__ float csf[NC_];
    __shared__ int cs[NC_];
    __shared__ float ctxL[NC_ * 33];
    __shared__ int ok[3];
    __shared__ int evid_sh;
    int tid = threadIdx.x;
    int b = blockIdx.x;
    if (tid < 3) ok[tid] = 1;
    if (tid == 0) evid_sh = 0;
    if (tid < NC_) cs[tid] = 0;
    __syncthreads();
    {
        const unsigned int* mi = (const unsigned int*)mask;
        int li32 = 1, lf32 = 1, li64 = 1;
        for (int i = tid; i < 4096; i += 1024) {
            unsigned int v = mi[i];
            li32 &= (v <= 1u);
            lf32 &= (v == 0u || v == 0x3F800000u);
            li64 &= ((i & 1) ? (v == 0u) : (v <= 1u));
        }
        if (!li32) atomicAnd(&ok[0], 0);
        if (!lf32) atomicAnd(&ok[1], 0);
        if (!li64) atomicAnd(&ok[2], 0);
    }
    __syncthreads();
    int layout = ok[2] ? 3 : (ok[0] ? 0 : (ok[1] ? 1 : 2));
    for (int i = tid; i < N_; i += 1024) {
        const float* zb = z + (size_t)b * K_ * N_ + i;
        int code = 0;
#pragma unroll
        for (int j = 0; j < K_; ++j) code |= (zb[j * N_] > 0.5f ? 1 : 0) << j;
        codesL[i] = (unsigned short)code;
        if (read_mask(mask, layout, b * N_ + i)) {
            atomicAdd(&cs[code], 1);
            atomicAdd(&evid_sh, 1);
        }
    }
    __syncthreads();
    if (tid < NC_) csf[tid] = (float)cs[tid];
    __syncthreads();
    int evid = evid_sh;
    float temp = fmaxf(temperature[0], 0.1f);
    float rinv = -1.0f / temp;
    int d = tid & 31;
    for (int qi = 0; qi < 8; ++qi) {
        int q = (qi << 5) + (tid >> 5);
        float num = 0.0f, den = 0.0f;
        for (int c = 0; c < NC_; ++c) {
            float cc = csf[c];
            float w = cc * __expf((float)__popc(q ^ c) * rinv);
            den += w;
            num = fmaf(w, V[c * DV_ + d], num);
        }
        ctxL[q * 33 + d] = (evid == 0) ? mask_value[d] : num / den;
    }
    __syncthreads();
    for (int idx = tid; idx < DV_ * N_; idx += 1024) {
        int dd = idx >> 12;
        int n = idx & (N_ - 1);
        out[(size_t)b * DV_ * N_ + idx] = ctxL[codesL[n] * 33 + dd];
    }
}

extern "C" void kernel_launch(void* const* d_in, const int* in_sizes, int n_in,
                              void* d_out, int out_size, void* d_ws, size_t ws_size,
                              hipStream_t stream) {
    const float* z    = (const float*)d_in[0];
    const void*  mask = d_in[1];
    const float* V    = (const float*)d_in[2];
    const float* mv   = (const float*)d_in[3];
    const float* temp = (const float*)d_in[4];
    float* out = (float*)d_out;

    if (ws_size >= (size_t)WS_COOP) {
        int* part = (int*)d_ws;
        void* args[] = {(void*)&z, (void*)&mask, (void*)&V, (void*)&mv,
                        (void*)&temp, (void*)&out, (void*)&part};
        hipError_t err = hipLaunchCooperativeKernel((const void*)coop_one,
                                                    dim3(B_ * 16), dim3(256),
                                                    args, 0, stream);
        if (err == hipSuccess) return;
        (void)hipGetLastError();  // clear sticky error, fall through
    }
    if (ws_size >= (size_t)WS_2K) {
        char* ws = (char*)d_ws;
        int*           part  = (int*)ws;
        unsigned char* codes = (unsigned char*)(ws + WS_OFF_CODES);
        k1_codes_hist<<<B_ * 16, 256, 0, stream>>>(z, mask, part, codes);
        k2_ctx_gather<<<B_ * 16, 256, 0, stream>>>(part, codes, V, mv, temp, out);
    } else {
        fused_all<<<B_, 1024, 0, stream>>>(z, mask, V, mv, temp, out);
    }
}

// Round 5
// 24.819 us; speedup vs baseline: 2.0501x; 2.0501x over previous
//
#include <hip/hip_runtime.h>

#define B_   4
#define K_   8
#define N_   4096       // H*W
#define DV_  32
#define NC_  256        // 2^K_

// ws: [0, 65536) int part_hist[64][256]; [65536, 81920) uchar codes[B_*N_]
#define WS_OFF_CODES 65536
#define WS_NEEDED    81920

__device__ __forceinline__ int read_mask(const void* m, int layout, int idx) {
    if (layout == 0) return ((const int*)m)[idx] != 0;
    if (layout == 1) return ((const float*)m)[idx] != 0.0f;
    if (layout == 3) return ((const int*)m)[2 * idx] != 0;  // int64 LE low word
    return ((const unsigned char*)m)[idx] != 0;
}

// Every block scans the same leading 16 KB of the mask buffer (safe under all
// candidate layouts; the u8 buffer is exactly 16 KB) -> identical verdict in
// every block, deterministic.
__device__ __forceinline__ int detect_layout(const void* mask, int tid) {
    __shared__ int ok[3];  // 0:i32, 1:f32, 2:i64
    if (tid < 3) ok[tid] = 1;
    __syncthreads();
    const unsigned int* mi = (const unsigned int*)mask;
    int li32 = 1, lf32 = 1, li64 = 1;
    for (int i = tid; i < 4096; i += 256) {
        unsigned int v = mi[i];
        li32 &= (v <= 1u);
        lf32 &= (v == 0u || v == 0x3F800000u);
        li64 &= ((i & 1) ? (v == 0u) : (v <= 1u));
    }
    if (!li32) atomicAnd(&ok[0], 0);
    if (!lf32) atomicAnd(&ok[1], 0);
    if (!li64) atomicAnd(&ok[2], 0);
    __syncthreads();
    return ok[2] ? 3 : (ok[0] ? 0 : (ok[1] ? 1 : 2));
}

// K1: layout detect + bit-pack codes + per-block evidence histogram.
// grid = B_*16, block = 256. No global atomics, no pre-zeroing needed.
__global__ void k1_codes_hist(const float* __restrict__ z, const void* mask,
                              int* __restrict__ part, unsigned char* __restrict__ codes) {
    __shared__ int hist[NC_];
    int tid = threadIdx.x;
    int b = blockIdx.x >> 4;
    int n = ((blockIdx.x & 15) << 8) + tid;
    int layout = detect_layout(mask, tid);   // contains syncthreads
    hist[tid] = 0;
    __syncthreads();
    const float* zb = z + (size_t)b * K_ * N_ + n;
    int code = 0;
#pragma unroll
    for (int j = 0; j < K_; ++j) code |= (zb[j * N_] > 0.5f ? 1 : 0) << j;
    codes[b * N_ + n] = (unsigned char)code;
    if (read_mask(mask, layout, b * N_ + n)) atomicAdd(&hist[code], 1);
    __syncthreads();
    part[blockIdx.x * NC_ + tid] = hist[tid];
}

// K2: reduce histograms -> Kronecker-butterfly ctx -> gather + transposed write.
// W[q,c] = t^popc(q^c) = [[1,t],[t,1]]^{(x)8}; 8 butterfly stages over 256x33
// (32 V-columns + 1 denominator column). grid = B_*16, block = 256.
__global__ void __launch_bounds__(256)
k2_ctx_gather(const int* __restrict__ part, const unsigned char* __restrict__ codes,
              const float* __restrict__ V, const float* __restrict__ mv,
              const float* __restrict__ temperature, float* __restrict__ out) {
    __shared__ float X[NC_ * 33];   // row stride 33 -> lane-distinct banks
    __shared__ int red[4];
    int tid = threadIdx.x;
    int b = blockIdx.x >> 4;
    int slice = blockIdx.x & 15;
    int mycode = codes[b * N_ + (slice << 8) + tid];

    // sum this batch's 16 private histograms (bin = tid)
    int c = 0;
#pragma unroll
    for (int j = 0; j < 16; ++j) c += part[(b * 16 + j) * NC_ + tid];
    float cf = (float)c;

    // evidence count = sum over bins (wave shuffle + LDS across 4 waves)
    int s = c;
#pragma unroll
    for (int off = 32; off; off >>= 1) s += __shfl_down(s, off);
    if ((tid & 63) == 0) red[tid >> 6] = s;
    __syncthreads();
    int evid = red[0] + red[1] + red[2] + red[3];

    float temp = fmaxf(temperature[0], 0.1f);
    float t = __expf(-1.0f / temp);

    // init own row: X[tid][0..31] = cnt[tid]*V[tid][d], X[tid][32] = cnt[tid]
    // bank(tid*33+r) = (tid+r)%32 -> conflict-free per r-step
#pragma unroll
    for (int r = 0; r < 33; ++r)
        X[tid * 33 + r] = (r < DV_) ? cf * V[tid * DV_ + r] : cf;
    __syncthreads();

    // 8 butterfly stages: x0' = x0 + t*x1 ; x1' = t*x0 + x1
#pragma unroll
    for (int stg = 0; stg < 8; ++stg) {
        int bit = 1 << stg;
        for (int p = tid; p < 128 * 33; p += 256) {
            int pi = p / 33, col = p - pi * 33;
            int c0 = ((pi >> stg) << (stg + 1)) | (pi & (bit - 1));
            int i0 = c0 * 33 + col, i1 = i0 + bit * 33;
            float x0 = X[i0], x1 = X[i1];
            X[i0] = fmaf(t, x1, x0);
            X[i1] = fmaf(t, x0, x1);
        }
        __syncthreads();
    }

    // gather by code, write transposed (out[b][d][n], n contiguous per wave)
    float* ob = out + (size_t)b * DV_ * N_ + (slice << 8) + tid;
    if (evid == 0) {
#pragma unroll
        for (int d = 0; d < DV_; ++d) ob[d * N_] = mv[d];
    } else {
        float rden = 1.0f / X[mycode * 33 + DV_];
#pragma unroll
        for (int d = 0; d < DV_; ++d) ob[d * N_] = X[mycode * 33 + d] * rden;
    }
}

// Fallback: fully fused, zero workspace. grid = B_, block = 1024.
__global__ void __launch_bounds__(1024)
fused_all(const float* __restrict__ z, const void* mask, const float* __restrict__ V,
          const float* __restrict__ mask_value, const float* __restrict__ temperature,
          float* __restrict__ out) {
    __shared__ unsigned short codesL[N_];
    __shared__ float csf[NC_];
    __shared__ int cs[NC_];
    __shared__ float ctxL[NC_ * 33];
    __shared__ int ok[3];
    __shared__ int evid_sh;
    int tid = threadIdx.x;
    int b = blockIdx.x;
    if (tid < 3) ok[tid] = 1;
    if (tid == 0) evid_sh = 0;
    if (tid < NC_) cs[tid] = 0;
    __syncthreads();
    {
        const unsigned int* mi = (const unsigned int*)mask;
        int li32 = 1, lf32 = 1, li64 = 1;
        for (int i = tid; i < 4096; i += 1024) {
            unsigned int v = mi[i];
            li32 &= (v <= 1u);
            lf32 &= (v == 0u || v == 0x3F800000u);
            li64 &= ((i & 1) ? (v == 0u) : (v <= 1u));
        }
        if (!li32) atomicAnd(&ok[0], 0);
        if (!lf32) atomicAnd(&ok[1], 0);
        if (!li64) atomicAnd(&ok[2], 0);
    }
    __syncthreads();
    int layout = ok[2] ? 3 : (ok[0] ? 0 : (ok[1] ? 1 : 2));
    for (int i = tid; i < N_; i += 1024) {
        const float* zb = z + (size_t)b * K_ * N_ + i;
        int code = 0;
#pragma unroll
        for (int j = 0; j < K_; ++j) code |= (zb[j * N_] > 0.5f ? 1 : 0) << j;
        codesL[i] = (unsigned short)code;
        if (read_mask(mask, layout, b * N_ + i)) {
            atomicAdd(&cs[code], 1);
            atomicAdd(&evid_sh, 1);
        }
    }
    __syncthreads();
    if (tid < NC_) csf[tid] = (float)cs[tid];
    __syncthreads();
    int evid = evid_sh;
    float temp = fmaxf(temperature[0], 0.1f);
    float rinv = -1.0f / temp;
    int d = tid & 31;
    for (int qi = 0; qi < 8; ++qi) {
        int q = (qi << 5) + (tid >> 5);
        float num = 0.0f, den = 0.0f;
        for (int c = 0; c < NC_; ++c) {
            float cc = csf[c];
            float w = cc * __expf((float)__popc(q ^ c) * rinv);
            den += w;
            num = fmaf(w, V[c * DV_ + d], num);
        }
        ctxL[q * 33 + d] = (evid == 0) ? mask_value[d] : num / den;
    }
    __syncthreads();
    for (int idx = tid; idx < DV_ * N_; idx += 1024) {
        int dd = idx >> 12;
        int n = idx & (N_ - 1);
        out[(size_t)b * DV_ * N_ + idx] = ctxL[codesL[n] * 33 + dd];
    }
}

extern "C" void kernel_launch(void* const* d_in, const int* in_sizes, int n_in,
                              void* d_out, int out_size, void* d_ws, size_t ws_size,
                              hipStream_t stream) {
    const float* z    = (const float*)d_in[0];
    const void*  mask = d_in[1];
    const float* V    = (const float*)d_in[2];
    const float* mv   = (const float*)d_in[3];
    const float* temp = (const float*)d_in[4];
    float* out = (float*)d_out;

    if (ws_size >= (size_t)WS_NEEDED) {
        char* ws = (char*)d_ws;
        int*           part  = (int*)ws;
        unsigned char* codes = (unsigned char*)(ws + WS_OFF_CODES);
        k1_codes_hist<<<B_ * 16, 256, 0, stream>>>(z, mask, part, codes);
        k2_ctx_gather<<<B_ * 16, 256, 0, stream>>>(part, codes, V, mv, temp, out);
    } else {
        fused_all<<<B_, 1024, 0, stream>>>(z, mask, V, mv, temp, out);
    }
}